// Round 3
// baseline (820.307 us; speedup 1.0000x reference)
//
#include <hip/hip_runtime.h>
#include <hip/hip_fp16.h>
#include <cstdint>
#include <cstddef>

#define GLOBAL_AS __attribute__((address_space(1)))
#define LDS_AS    __attribute__((address_space(3)))

typedef __attribute__((ext_vector_type(8))) _Float16 f16x8;
typedef __attribute__((ext_vector_type(4))) float    f32x4;

__device__ __forceinline__ void gload_lds16(const void* g, void* l) {
    __builtin_amdgcn_global_load_lds((const GLOBAL_AS void*)g,
                                     (LDS_AS void*)l, 16, 0, 0);
}

// fp16 quantizer == reference fp_quantize_ste(exp=5, sig=10): RNE + saturate.
__device__ __forceinline__ __half qcvt(float x) {
    x = fminf(fmaxf(x, -65504.f), 65504.f);
    return __float2half(x);   // v_cvt_f16_f32: RNE, subnormals handled
}

__global__ void quant_f32_to_f16(const float* __restrict__ in,
                                 __half* __restrict__ out, int n4) {
    const int stride = gridDim.x * blockDim.x;
    for (int i = blockIdx.x * blockDim.x + threadIdx.x; i < n4; i += stride) {
        const float4 f = reinterpret_cast<const float4*>(in)[i];
        union { __half h[4]; uint2 u; } p;
        p.h[0] = qcvt(f.x);
        p.h[1] = qcvt(f.y);
        p.h[2] = qcvt(f.z);
        p.h[3] = qcvt(f.w);
        reinterpret_cast<uint2*>(out)[i] = p.u;
    }
}

// ---------------------------------------------------------------------------
// 256x256 tile, BK=64, 8 waves (2Mx4N), 8-phase schedule with
// one-phase-lookahead fragment loads (LDS reads overlap MFMA) and
// register-resident B fragments (24 KiB LDS reads /wave/tile, not 28).
//
// Phases: P0=(A0,B0) P1=(A0,B1) P2=(A1,B1) P3=(A1,B0)
// Frag regs: afX=A0, afY=A1 (reloaded per tile), bfB=B1,
//            B0 double-buffered by tile parity (B0e/B0o) since P3 both
//            uses B0(t) and loads B0(t+1).
// Per-phase pre-region (before barrier1): ds_reads for NEXT phase + STAGE.
// No blanket lgkmcnt(0) — compiler emits exact counted waits per frag use,
// so the LDS unit serves reads while the MFMA cluster executes.
// Cross-tile reads (A0,B0 of t+1) sit after P3's vmcnt(6)+barrier, pinned
// before the MFMA cluster via sched_group_barrier.
// ---------------------------------------------------------------------------
__global__ __launch_bounds__(512, 2) void gemm_f16_8phase(
    const __half* __restrict__ A, const __half* __restrict__ B,
    const __half* __restrict__ bias, float* __restrict__ C,
    int M, int N, int K)
{
    __shared__ __align__(16) __half lds[2][2][2][8192];   // 128 KiB

    const int tid  = threadIdx.x;
    const int lane = tid & 63;
    const int wid  = tid >> 6;     // 8 waves
    const int wr   = wid >> 2;     // 0..1 (M)
    const int wc   = wid & 3;      // 0..3 (N)
    const int fr   = lane & 15;
    const int fq   = lane >> 4;

    // bijective XCD swizzle (m204)
    const int nwg = gridDim.x;
    const int qq = nwg >> 3, rr = nwg & 7;
    const int xcd = blockIdx.x & 7, idx = blockIdx.x >> 3;
    const int wgid = (xcd < rr ? xcd * (qq + 1)
                               : rr * (qq + 1) + (xcd - rr) * qq) + idx;
    const int nbn = N >> 8;
    const int tile_m = (wgid / nbn) << 8;
    const int tile_n = (wgid % nbn) << 8;

    // ---- staging source coords (inverse of LDS swizzle, per thread) ----
    const int wbyte = (lane * 16) ^ (((lane >> 5) & 1) << 5);
    const int srow  = ((wid >> 1) << 4) + (wbyte >> 6);   // 0..63
    const int scb   = ((wid & 1) << 6) + (wbyte & 63);    // col byte 0..127
    const char* gA0 = (const char*)A + (size_t)(tile_m + srow) * K * 2 + scb;
    const char* gB0 = (const char*)B + (size_t)(tile_n + srow) * K * 2 + scb;
    const size_t rstep = (size_t)64  * K * 2;   // +64 rows
    const size_t hstep = (size_t)128 * K * 2;   // +1 half (128 rows)
    const int ldst = tid * 16;                  // linear LDS dest byte

    // ---- fragment-read byte offsets (st_16x32 swizzled) ----
    const int woff  = (fr * 64 + fq * 16) ^ (((fr >> 3) & 1) << 5);
    const int aoff  = wr * 8192 + woff;     // + m*2048 + kk*1024
    const int boff  = wc * 4096 + woff;     // + n*2048 + kk*1024

    f32x4 acc[2][2][4][2];
#pragma unroll
    for (int qa = 0; qa < 2; ++qa)
#pragma unroll
        for (int qb = 0; qb < 2; ++qb)
#pragma unroll
            for (int m = 0; m < 4; ++m)
#pragma unroll
                for (int n = 0; n < 2; ++n)
                    acc[qa][qb][m][n] = (f32x4){0.f, 0.f, 0.f, 0.f};

    f16x8 afX[4][2], afY[4][2];        // A half-0 / half-1 fragments
    f16x8 bfB[2][2];                    // B1 fragments
    f16x8 b0e[2][2], b0o[2][2];         // B0 fragments, tile-parity buffers

#define STAGE_A(bufi, h, kt) do {                                          \
        char* l_ = (char*)(&lds[bufi][0][h][0]) + ldst;                    \
        const char* g_ = gA0 + (size_t)(kt) * 128 + ((h) ? hstep : 0);     \
        gload_lds16(g_, l_);                                               \
        gload_lds16(g_ + rstep, l_ + 8192);                                \
    } while (0)

#define STAGE_B(bufi, h, kt) do {                                          \
        char* l_ = (char*)(&lds[bufi][1][h][0]) + ldst;                    \
        const char* g_ = gB0 + (size_t)(kt) * 128 + ((h) ? hstep : 0);     \
        gload_lds16(g_, l_);                                               \
        gload_lds16(g_ + rstep, l_ + 8192);                                \
    } while (0)

#define LDGA(dst, bufi, qa) do {                                           \
        const char* lb_ = (const char*)(&lds[bufi][0][qa][0]) + aoff;      \
        _Pragma("unroll")                                                  \
        for (int m_ = 0; m_ < 4; ++m_) {                                   \
            dst[m_][0] = *(const f16x8*)(lb_ + m_ * 2048);                 \
            dst[m_][1] = *(const f16x8*)(lb_ + m_ * 2048 + 1024);          \
        }                                                                  \
    } while (0)

#define LDGB(dst, bufi, hb) do {                                           \
        const char* lb_ = (const char*)(&lds[bufi][1][hb][0]) + boff;      \
        _Pragma("unroll")                                                  \
        for (int n_ = 0; n_ < 2; ++n_) {                                   \
            dst[n_][0] = *(const f16x8*)(lb_ + n_ * 2048);                 \
            dst[n_][1] = *(const f16x8*)(lb_ + n_ * 2048 + 1024);          \
        }                                                                  \
    } while (0)

#define MMA(qa, qb, AF, BF)                                                \
    __builtin_amdgcn_s_setprio(1);                                         \
    _Pragma("unroll")                                                      \
    for (int m_ = 0; m_ < 4; ++m_) {                                       \
        _Pragma("unroll")                                                  \
        for (int n_ = 0; n_ < 2; ++n_) {                                   \
            acc[qa][qb][m_][n_] = __builtin_amdgcn_mfma_f32_16x16x32_f16(  \
                AF[m_][0], BF[n_][0], acc[qa][qb][m_][n_], 0, 0, 0);       \
            acc[qa][qb][m_][n_] = __builtin_amdgcn_mfma_f32_16x16x32_f16(  \
                AF[m_][1], BF[n_][1], acc[qa][qb][m_][n_], 0, 0, 0);       \
        }                                                                  \
    }                                                                      \
    __builtin_amdgcn_s_setprio(0);

#define PH_BAR()                                                           \
    asm volatile("" ::: "memory");                                         \
    __builtin_amdgcn_s_barrier();                                          \
    asm volatile("" ::: "memory")

#define SGB_READS_THEN_MMA()                                               \
    __builtin_amdgcn_sched_group_barrier(0x100, 12, 0);                    \
    __builtin_amdgcn_sched_group_barrier(0x008, 16, 0)

    // Full steady-state tile. B0C = B0(t) regs, B0N = B0(t+1) regs.
#define TILE_FULL(cur, nxt, kt, B0C, B0N)                                  \
    LDGB(bfB, cur, 1); STAGE_B(nxt, 0, (kt) + 1);                          \
    PH_BAR(); MMA(0, 0, afX, B0C); PH_BAR();                               \
    LDGA(afY, cur, 1); STAGE_A(cur, 0, (kt) + 2);                          \
    PH_BAR(); MMA(0, 1, afX, bfB); PH_BAR();                               \
    STAGE_B(cur, 1, (kt) + 2);                                             \
    PH_BAR(); MMA(1, 1, afY, bfB); PH_BAR();                               \
    STAGE_A(cur, 1, (kt) + 2);                                             \
    asm volatile("s_waitcnt vmcnt(6)" ::: "memory");                       \
    PH_BAR();                                                              \
    LDGA(afX, nxt, 0); LDGB(B0N, nxt, 0);                                  \
    SGB_READS_THEN_MMA();                                                  \
    MMA(1, 0, afY, B0C); PH_BAR();

    // ---- prologue: stage tile0 fully + tile1 (A0,B1,A1); B0(1) in-loop ----
    STAGE_A(0, 0, 0); STAGE_B(0, 0, 0); STAGE_B(0, 1, 0); STAGE_A(0, 1, 0);
    STAGE_A(1, 0, 1); STAGE_B(1, 1, 1); STAGE_A(1, 1, 1);
    asm volatile("s_waitcnt vmcnt(6)" ::: "memory");   // tile0 arrived
    __builtin_amdgcn_s_barrier();
    asm volatile("" ::: "memory");
    LDGA(afX, 0, 0); LDGB(b0e, 0, 0);

    const int nt = K >> 6;              // even, >= 4 (guarded by launcher)
    for (int kt = 0; kt + 3 < nt; kt += 2) {
        TILE_FULL(0, 1, kt,     b0e, b0o);
        TILE_FULL(1, 0, kt + 1, b0o, b0e);
    }

    // ---- tile nt-2 (buf0, even): stage only B0(nt-1); drain at P3 ----
    LDGB(bfB, 0, 1); STAGE_B(1, 0, nt - 1);
    PH_BAR(); MMA(0, 0, afX, b0e); PH_BAR();
    LDGA(afY, 0, 1);
    PH_BAR(); MMA(0, 1, afX, bfB); PH_BAR();
    PH_BAR(); MMA(1, 1, afY, bfB); PH_BAR();
    asm volatile("s_waitcnt vmcnt(0)" ::: "memory");
    PH_BAR();
    LDGA(afX, 1, 0); LDGB(b0o, 1, 0);
    SGB_READS_THEN_MMA();
    MMA(1, 0, afY, b0e); PH_BAR();

    // ---- tile nt-1 (buf1, odd): pure compute ----
    LDGB(bfB, 1, 1);
    PH_BAR(); MMA(0, 0, afX, b0o); PH_BAR();
    LDGA(afY, 1, 1);
    PH_BAR(); MMA(0, 1, afX, bfB); PH_BAR();
    PH_BAR(); MMA(1, 1, afY, bfB); PH_BAR();
    PH_BAR(); MMA(1, 0, afY, b0o);

    // ---- epilogue: C/D layout col=lane&15, row=fq*4+reg (m89-verified) ----
    float bv[2][2];
#pragma unroll
    for (int qb = 0; qb < 2; ++qb)
#pragma unroll
        for (int n = 0; n < 2; ++n)
            bv[qb][n] = __half2float(
                bias[tile_n + qb * 128 + wc * 32 + n * 16 + fr]);

#pragma unroll
    for (int qa = 0; qa < 2; ++qa)
#pragma unroll
        for (int qb = 0; qb < 2; ++qb)
#pragma unroll
            for (int m = 0; m < 4; ++m)
#pragma unroll
                for (int n = 0; n < 2; ++n) {
                    const int col = tile_n + qb * 128 + wc * 32 + n * 16 + fr;
                    const int rowb = tile_m + qa * 128 + wr * 64 + m * 16 + fq * 4;
#pragma unroll
                    for (int r = 0; r < 4; ++r)
                        C[(size_t)(rowb + r) * N + col] =
                            acc[qa][qb][m][n][r] + bv[qb][n];
                }

#undef STAGE_A
#undef STAGE_B
#undef LDGA
#undef LDGB
#undef MMA
#undef PH_BAR
#undef SGB_READS_THEN_MMA
#undef TILE_FULL
}

// ---------------------------------------------------------------------------
// Insurance fallback (shape or ws mismatch): fused naive, slow but correct.
// ---------------------------------------------------------------------------
__global__ void qat_gemm_naive(const float* __restrict__ A,
                               const float* __restrict__ B,
                               const float* __restrict__ bias,
                               float* __restrict__ C, int M, int N, int K) {
    const int col = blockIdx.x * blockDim.x + threadIdx.x;
    const int row = blockIdx.y;
    if (col >= N || row >= M) return;
    float s = 0.f;
    for (int k = 0; k < K; ++k) {
        float a = __half2float(qcvt(A[(size_t)row * K + k]));
        float b = __half2float(qcvt(B[(size_t)col * K + k]));
        s += a * b;
    }
    C[(size_t)row * N + col] = s + __half2float(qcvt(bias[col]));
}

// ---------------------------------------------------------------------------
extern "C" void kernel_launch(void* const* d_in, const int* in_sizes, int n_in,
                              void* d_out, int out_size, void* d_ws,
                              size_t ws_size, hipStream_t stream) {
    const float* x = (const float*)d_in[0];
    const float* w = (const float*)d_in[1];
    const float* b = (const float*)d_in[2];
    float* out = (float*)d_out;

    const int xn = in_sizes[0];     // M*K
    const int wn = in_sizes[1];     // N*K
    const int N  = in_sizes[2];     // 4096
    const int K  = wn / N;          // 4096
    const int M  = xn / K;          // 8192

    const size_t need = (size_t)(xn + wn + N) * sizeof(__half);
    const bool ok = (M % 256 == 0) && (N % 256 == 0) &&
                    (K % 128 == 0) && (K >= 256);

    if (ws_size >= need && ok) {
        __half* xq = (__half*)d_ws;
        __half* wq = xq + xn;
        __half* bq = wq + wn;

        int blk;
        blk = (xn / 4 + 255) / 256; if (blk > 2048) blk = 2048;
        quant_f32_to_f16<<<blk, 256, 0, stream>>>(x, xq, xn / 4);
        blk = (wn / 4 + 255) / 256; if (blk > 2048) blk = 2048;
        quant_f32_to_f16<<<blk, 256, 0, stream>>>(w, wq, wn / 4);
        blk = (N / 4 + 255) / 256; if (blk > 2048) blk = 2048;
        quant_f32_to_f16<<<blk, 256, 0, stream>>>(b, bq, N / 4);

        dim3 grid((M / 256) * (N / 256));
        gemm_f16_8phase<<<grid, 512, 0, stream>>>(xq, wq, bq, out, M, N, K);
    } else {
        dim3 grid((N + 255) / 256, M);
        qat_gemm_naive<<<grid, 256, 0, stream>>>(x, w, b, out, M, N, K);
    }
}

// Round 4
// 286.460 us; speedup vs baseline: 2.8636x; 2.8636x over previous
//
#include <hip/hip_runtime.h>
#include <hip/hip_fp16.h>
#include <cstdint>
#include <cstddef>

#define GLOBAL_AS __attribute__((address_space(1)))
#define LDS_AS    __attribute__((address_space(3)))

typedef __attribute__((ext_vector_type(8))) _Float16 f16x8;
typedef __attribute__((ext_vector_type(4))) float    f32x4;

__device__ __forceinline__ void gload_lds16(const void* g, void* l) {
    __builtin_amdgcn_global_load_lds((const GLOBAL_AS void*)g,
                                     (LDS_AS void*)l, 16, 0, 0);
}

// fp16 quantizer == reference fp_quantize_ste(exp=5, sig=10): RNE + saturate.
__device__ __forceinline__ __half qcvt(float x) {
    x = fminf(fmaxf(x, -65504.f), 65504.f);
    return __float2half(x);   // v_cvt_f16_f32: RNE, subnormals handled
}

// Fused quantization of x and w (both f32 -> f16), one launch, grid-stride.
__global__ void quant_xw_f32_to_f16(const float* __restrict__ xin, int x4,
                                    const float* __restrict__ win, int w4,
                                    __half* __restrict__ xout,
                                    __half* __restrict__ wout) {
    const int stride = gridDim.x * blockDim.x;
    const int tot = x4 + w4;
    for (int i = blockIdx.x * blockDim.x + threadIdx.x; i < tot; i += stride) {
        const bool isx = (i < x4);
        const int  j   = isx ? i : i - x4;
        const float4 f = reinterpret_cast<const float4*>(isx ? xin : win)[j];
        union { __half h[4]; uint2 u; } p;
        p.h[0] = qcvt(f.x);
        p.h[1] = qcvt(f.y);
        p.h[2] = qcvt(f.z);
        p.h[3] = qcvt(f.w);
        reinterpret_cast<uint2*>(isx ? xout : wout)[j] = p.u;
    }
}

// ---------------------------------------------------------------------------
// 256x256 tile, BK=64, 8 waves (2Mx4N), 8-phase schedule (m201 template),
// barriers WITHOUT blanket lgkmcnt(0): compiler emits counted per-use waits
// so the MFMA cluster overlaps the LDS read tail. B0 fragments stay in
// registers across the tile (no P3 re-read; P3 is pure MFMA).
//
// Phases: P0=(A0,B0) P1=(A0,B1) P2=(A1,B1) P3=(A1,B0)
// Reads/wave: P0: bf0(4)+af(8)  P1: bf1(4)  P2: af<-A1(8)  P3: none
// Staging:    P0: B0(t+1)->nxt  P1: A0(t+2)->cur  P2: B1(t+2)->cur
//             P3: A1(t+2)->cur, then vmcnt(6) (tile t+1 fully retired).
// WAR safety: each region's reads are consumed by that phase's MFMAs
// (compiler waits) -> complete before the closing barrier; the STAGE that
// overwrites the region is always issued after that barrier.
// ---------------------------------------------------------------------------
__global__ __launch_bounds__(512, 2) void gemm_f16_8phase(
    const __half* __restrict__ A, const __half* __restrict__ B,
    const float* __restrict__ bias, float* __restrict__ C,
    int M, int N, int K)
{
    __shared__ __align__(16) __half lds[2][2][2][8192];   // 128 KiB

    const int tid  = threadIdx.x;
    const int lane = tid & 63;
    const int wid  = tid >> 6;     // 8 waves
    const int wr   = wid >> 2;     // 0..1 (M)
    const int wc   = wid & 3;      // 0..3 (N)
    const int fr   = lane & 15;
    const int fq   = lane >> 4;

    // bijective XCD swizzle (m204)
    const int nwg = gridDim.x;
    const int qq = nwg >> 3, rr = nwg & 7;
    const int xcd = blockIdx.x & 7, idx = blockIdx.x >> 3;
    const int wgid = (xcd < rr ? xcd * (qq + 1)
                               : rr * (qq + 1) + (xcd - rr) * qq) + idx;
    const int nbn = N >> 8;
    const int tile_m = (wgid / nbn) << 8;
    const int tile_n = (wgid % nbn) << 8;

    // ---- staging source coords (inverse of LDS swizzle, per thread) ----
    const int wbyte = (lane * 16) ^ (((lane >> 5) & 1) << 5);
    const int srow  = ((wid >> 1) << 4) + (wbyte >> 6);   // 0..63
    const int scb   = ((wid & 1) << 6) + (wbyte & 63);    // col byte 0..127
    const char* gA0 = (const char*)A + (size_t)(tile_m + srow) * K * 2 + scb;
    const char* gB0 = (const char*)B + (size_t)(tile_n + srow) * K * 2 + scb;
    const size_t rstep = (size_t)64  * K * 2;   // +64 rows
    const size_t hstep = (size_t)128 * K * 2;   // +1 half (128 rows)
    const int ldst = tid * 16;                  // linear LDS dest byte

    // ---- fragment-read byte offsets (st_16x32 swizzled) ----
    const int woff  = (fr * 64 + fq * 16) ^ (((fr >> 3) & 1) << 5);
    const int aoff  = wr * 8192 + woff;     // + m*2048 + kk*1024
    const int boff  = wc * 4096 + woff;     // + n*2048 + kk*1024

    f32x4 acc[2][2][4][2];
#pragma unroll
    for (int qa = 0; qa < 2; ++qa)
#pragma unroll
        for (int qb = 0; qb < 2; ++qb)
#pragma unroll
            for (int m = 0; m < 4; ++m)
#pragma unroll
                for (int n = 0; n < 2; ++n)
                    acc[qa][qb][m][n] = (f32x4){0.f, 0.f, 0.f, 0.f};

    f16x8 af[4][2];        // A fragments (half 0, then reloaded for half 1)
    f16x8 bf0[2][2];       // B0 fragments (live whole tile: P0 and P3)
    f16x8 bf1[2][2];       // B1 fragments (P1, P2)

#define STAGE_A(bufi, h, kt) do {                                          \
        char* l_ = (char*)(&lds[bufi][0][h][0]) + ldst;                    \
        const char* g_ = gA0 + (size_t)(kt) * 128 + ((h) ? hstep : 0);     \
        gload_lds16(g_, l_);                                               \
        gload_lds16(g_ + rstep, l_ + 8192);                                \
    } while (0)

#define STAGE_B(bufi, h, kt) do {                                          \
        char* l_ = (char*)(&lds[bufi][1][h][0]) + ldst;                    \
        const char* g_ = gB0 + (size_t)(kt) * 128 + ((h) ? hstep : 0);     \
        gload_lds16(g_, l_);                                               \
        gload_lds16(g_ + rstep, l_ + 8192);                                \
    } while (0)

#define LDGA(bufi, qa) do {                                                \
        const char* lb_ = (const char*)(&lds[bufi][0][qa][0]) + aoff;      \
        _Pragma("unroll")                                                  \
        for (int m_ = 0; m_ < 4; ++m_) {                                   \
            af[m_][0] = *(const f16x8*)(lb_ + m_ * 2048);                  \
            af[m_][1] = *(const f16x8*)(lb_ + m_ * 2048 + 1024);           \
        }                                                                  \
    } while (0)

#define LDGB(dst, bufi, hb) do {                                           \
        const char* lb_ = (const char*)(&lds[bufi][1][hb][0]) + boff;      \
        _Pragma("unroll")                                                  \
        for (int n_ = 0; n_ < 2; ++n_) {                                   \
            dst[n_][0] = *(const f16x8*)(lb_ + n_ * 2048);                 \
            dst[n_][1] = *(const f16x8*)(lb_ + n_ * 2048 + 1024);          \
        }                                                                  \
    } while (0)

#define MMA(qa, qb, BF)                                                    \
    __builtin_amdgcn_s_setprio(1);                                         \
    _Pragma("unroll")                                                      \
    for (int m_ = 0; m_ < 4; ++m_) {                                       \
        _Pragma("unroll")                                                  \
        for (int n_ = 0; n_ < 2; ++n_) {                                   \
            acc[qa][qb][m_][n_] = __builtin_amdgcn_mfma_f32_16x16x32_f16(  \
                af[m_][0], BF[n_][0], acc[qa][qb][m_][n_], 0, 0, 0);       \
            acc[qa][qb][m_][n_] = __builtin_amdgcn_mfma_f32_16x16x32_f16(  \
                af[m_][1], BF[n_][1], acc[qa][qb][m_][n_], 0, 0, 0);       \
        }                                                                  \
    }                                                                      \
    __builtin_amdgcn_s_setprio(0);

// barrier only — NO lgkmcnt(0); compiler emits counted per-use waits
#define PH_BAR()                                                           \
    asm volatile("" ::: "memory");                                         \
    __builtin_amdgcn_s_barrier();                                          \
    asm volatile("" ::: "memory")

#define TILE_FULL(cur, nxt, kt)                                            \
    LDGB(bf0, cur, 0); LDGA(cur, 0); STAGE_B(nxt, 0, (kt) + 1);            \
    PH_BAR(); MMA(0, 0, bf0); PH_BAR();                                    \
    LDGB(bf1, cur, 1); STAGE_A(cur, 0, (kt) + 2);                          \
    PH_BAR(); MMA(0, 1, bf1); PH_BAR();                                    \
    LDGA(cur, 1); STAGE_B(cur, 1, (kt) + 2);                               \
    PH_BAR(); MMA(1, 1, bf1); PH_BAR();                                    \
    STAGE_A(cur, 1, (kt) + 2);                                             \
    asm volatile("s_waitcnt vmcnt(6)" ::: "memory");                       \
    PH_BAR(); MMA(1, 0, bf0); PH_BAR();

    // ---- prologue: stage tile0 fully + tile1 (A0,B1,A1); B0(1) in-loop ----
    STAGE_A(0, 0, 0); STAGE_B(0, 0, 0); STAGE_B(0, 1, 0); STAGE_A(0, 1, 0);
    STAGE_A(1, 0, 1); STAGE_B(1, 1, 1); STAGE_A(1, 1, 1);
    asm volatile("s_waitcnt vmcnt(6)" ::: "memory");   // tile0 arrived
    __builtin_amdgcn_s_barrier();
    asm volatile("" ::: "memory");

    const int nt = K >> 6;              // even, >= 4 (guarded by launcher)
    for (int kt = 0; kt + 3 < nt; kt += 2) {
        TILE_FULL(0, 1, kt);
        TILE_FULL(1, 0, kt + 1);
    }

    // ---- tile nt-2 (buf0): stage only B0(nt-1); full drain at P3 ----
    LDGB(bf0, 0, 0); LDGA(0, 0); STAGE_B(1, 0, nt - 1);
    PH_BAR(); MMA(0, 0, bf0); PH_BAR();
    LDGB(bf1, 0, 1);
    PH_BAR(); MMA(0, 1, bf1); PH_BAR();
    LDGA(0, 1);
    PH_BAR(); MMA(1, 1, bf1); PH_BAR();
    asm volatile("s_waitcnt vmcnt(0)" ::: "memory");
    PH_BAR(); MMA(1, 0, bf0); PH_BAR();

    // ---- tile nt-1 (buf1): pure compute ----
    LDGB(bf0, 1, 0); LDGA(1, 0);
    PH_BAR(); MMA(0, 0, bf0); PH_BAR();
    LDGB(bf1, 1, 1);
    PH_BAR(); MMA(0, 1, bf1); PH_BAR();
    LDGA(1, 1);
    PH_BAR(); MMA(1, 1, bf1); PH_BAR();
    MMA(1, 0, bf0);

    // ---- epilogue: C/D layout col=lane&15, row=fq*4+reg (m89-verified) ----
    // bias quantized here (fp16 RNE) instead of a separate kernel.
    float bv[2][2];
#pragma unroll
    for (int qb = 0; qb < 2; ++qb)
#pragma unroll
        for (int n = 0; n < 2; ++n)
            bv[qb][n] = __half2float(qcvt(
                bias[tile_n + qb * 128 + wc * 32 + n * 16 + fr]));

#pragma unroll
    for (int qa = 0; qa < 2; ++qa)
#pragma unroll
        for (int qb = 0; qb < 2; ++qb)
#pragma unroll
            for (int m = 0; m < 4; ++m)
#pragma unroll
                for (int n = 0; n < 2; ++n) {
                    const int col = tile_n + qb * 128 + wc * 32 + n * 16 + fr;
                    const int rowb = tile_m + qa * 128 + wr * 64 + m * 16 + fq * 4;
#pragma unroll
                    for (int r = 0; r < 4; ++r)
                        C[(size_t)(rowb + r) * N + col] =
                            acc[qa][qb][m][n][r] + bv[qb][n];
                }

#undef STAGE_A
#undef STAGE_B
#undef LDGA
#undef LDGB
#undef MMA
#undef PH_BAR
#undef TILE_FULL
}

// ---------------------------------------------------------------------------
// Insurance fallback (shape or ws mismatch): fused naive, slow but correct.
// ---------------------------------------------------------------------------
__global__ void qat_gemm_naive(const float* __restrict__ A,
                               const float* __restrict__ B,
                               const float* __restrict__ bias,
                               float* __restrict__ C, int M, int N, int K) {
    const int col = blockIdx.x * blockDim.x + threadIdx.x;
    const int row = blockIdx.y;
    if (col >= N || row >= M) return;
    float s = 0.f;
    for (int k = 0; k < K; ++k) {
        float a = __half2float(qcvt(A[(size_t)row * K + k]));
        float b = __half2float(qcvt(B[(size_t)col * K + k]));
        s += a * b;
    }
    C[(size_t)row * N + col] = s + __half2float(qcvt(bias[col]));
}

// ---------------------------------------------------------------------------
extern "C" void kernel_launch(void* const* d_in, const int* in_sizes, int n_in,
                              void* d_out, int out_size, void* d_ws,
                              size_t ws_size, hipStream_t stream) {
    const float* x = (const float*)d_in[0];
    const float* w = (const float*)d_in[1];
    const float* b = (const float*)d_in[2];
    float* out = (float*)d_out;

    const int xn = in_sizes[0];     // M*K
    const int wn = in_sizes[1];     // N*K
    const int N  = in_sizes[2];     // 4096
    const int K  = wn / N;          // 4096
    const int M  = xn / K;          // 8192

    const size_t need = (size_t)(xn + wn) * sizeof(__half);
    const bool ok = (M % 256 == 0) && (N % 256 == 0) &&
                    (K % 128 == 0) && (K >= 256);

    if (ws_size >= need && ok) {
        __half* xq = (__half*)d_ws;
        __half* wq = xq + xn;

        const int x4 = xn / 4, w4 = wn / 4;
        int blk = ((x4 + w4) + 255) / 256; if (blk > 2048) blk = 2048;
        quant_xw_f32_to_f16<<<blk, 256, 0, stream>>>(x, x4, w, w4, xq, wq);

        dim3 grid((M / 256) * (N / 256));
        gemm_f16_8phase<<<grid, 512, 0, stream>>>(xq, wq, b, out, M, N, K);
    } else {
        dim3 grid((N + 255) / 256, M);
        qat_gemm_naive<<<grid, 256, 0, stream>>>(x, w, b, out, M, N, K);
    }
}